// Round 21
// baseline (351.830 us; speedup 1.0000x reference)
//
#include <hip/hip_runtime.h>

#define BB 64
#define HH 512
#define WW 512
#define PLANE (HH * WW)
#define N_CHEBY 15
#define FD 5
#define RR 32
#define NS (HH / RR)          // 16 stripes (conv)
#define STEPS (RR + 2 * FD)   // 42
#define RSLOTS 8              // f-ring depth: power of 2 -> '&7' not '%6'

struct F8 { float v[8]; };

// wave-wide lane shifts with zero fill at wave edge (= plane column padding)
__device__ __forceinline__ float wshr1(float x) {  // lane i <- lane i-1; lane0 <- 0
    return __int_as_float(__builtin_amdgcn_update_dpp(
        0, __float_as_int(x), 0x138, 0xF, 0xF, true));
}
__device__ __forceinline__ float wshl1(float x) {  // lane i <- lane i+1; lane63 <- 0
    return __int_as_float(__builtin_amdgcn_update_dpp(
        0, __float_as_int(x), 0x130, 0xF, 0xF, true));
}

// lane owns cols [8*lane, 8*lane+8)
__device__ __forceinline__ F8 ldrow(const float* plane, int y, int lane, bool ok) {
    F8 r;
    if (ok) {
        const float4* p =
            reinterpret_cast<const float4*>(plane + (size_t)y * WW + (lane << 3));
        const float4 a = p[0], b = p[1];
        r.v[0] = a.x; r.v[1] = a.y; r.v[2] = a.z; r.v[3] = a.w;
        r.v[4] = b.x; r.v[5] = b.y; r.v[6] = b.z; r.v[7] = b.w;
    } else {
#pragma unroll
        for (int i = 0; i < 8; ++i) r.v[i] = 0.f;
    }
    return r;
}

__device__ __forceinline__ void racc8(const F8& r, float k0, float k1, float k2,
                                      float acc[8]) {
    const float lf = wshr1(r.v[7]);   // col 8L-1
    const float rt = wshl1(r.v[0]);   // col 8L+8
    acc[0] = fmaf(k0, lf, fmaf(k1, r.v[0], fmaf(k2, r.v[1], acc[0])));
#pragma unroll
    for (int c = 1; c < 7; ++c)
        acc[c] = fmaf(k0, r.v[c-1], fmaf(k1, r.v[c], fmaf(k2, r.v[c+1], acc[c])));
    acc[7] = fmaf(k0, r.v[6], fmaf(k1, r.v[7], fmaf(k2, rt, acc[7])));
}

// ---------------------------------------------------------------------------
// Barrier-free fused power pass (CHAMPION config: FD=5 @ RR=32, lb(256,1),
// grid 256 — ~31 us/pass). Wave owns one stripe; lag-1 level chain; DPP
// halos; pure-register (no LDS, no barriers).
// mz = stripe max|v_{FD-1}|, mw = stripe max|v_FD|. out==null -> no store.
// ---------------------------------------------------------------------------
__global__ __launch_bounds__(256, 1) void conv_wave(
    const float* __restrict__ in, const float* __restrict__ kern,
    const float* __restrict__ pm_prev, float* __restrict__ out,
    float* __restrict__ pmw, float* __restrict__ pmz)
{
    const int lane = threadIdx.x & 63;
    const int wid  = threadIdx.x >> 6;
    const int b = blockIdx.y;
    const int stripe = (blockIdx.x << 2) + wid;
    const int ytop = stripe * RR;

    float invv = 1.f;
    if (pm_prev) {
        float v = (lane < NS) ? pm_prev[b * NS + lane] : 0.f;
#pragma unroll
        for (int o = 32; o; o >>= 1) v = fmaxf(v, __shfl_xor(v, o, 64));
        invv = 1.f / v;
    }

    const float* kb = kern + b * 9;
    const float k00=kb[0],k01=kb[1],k02=kb[2],k10=kb[3],k11=kb[4],k12=kb[5],
                k20=kb[6],k21=kb[7],k22=kb[8];
    const float* ip = in + (size_t)b * PLANE;
    float* op = out ? out + (size_t)b * PLANE : nullptr;

    F8 u2 = {}, u1 = {};
    F8 lt[FD - 1] = {}, lm[FD - 1] = {};
    float mz = 0.f, mw = 0.f;
    F8 u0 = ldrow(ip, ytop - FD, lane, (unsigned)(ytop - FD) < HH);

#pragma unroll 6
    for (int p = 0; p < STEPS; ++p) {
        const int yL = ytop - FD + p;
        F8 un = ldrow(ip, yL + 1, lane,
                      (p < STEPS - 1) && ((unsigned)(yL + 1) < HH));

        F8 nw[FD - 1];
        {   // level 1: row y = yL-1
            float acc[8] = {0,0,0,0,0,0,0,0};
            racc8(u2, k00,k01,k02, acc);
            racc8(u1, k10,k11,k12, acc);
            racc8(u0, k20,k21,k22, acc);
            const int y = yL - 1;
            const bool act = (y >= ytop - (FD-1)) && (y <= ytop + RR + FD - 2)
                          && ((unsigned)y < HH);
#pragma unroll
            for (int c = 0; c < 8; ++c) nw[0].v[c] = act ? acc[c] * invv : 0.f;
        }
#pragma unroll
        for (int j = 2; j <= FD; ++j) {
            float acc[8] = {0,0,0,0,0,0,0,0};
            racc8(lt[j-2], k00,k01,k02, acc);
            racc8(lm[j-2], k10,k11,k12, acc);
            racc8(nw[j-2], k20,k21,k22, acc);
            const int y = yL - j;
            if (j < FD) {
                const bool act = (y >= ytop - (FD-j)) && (y <= ytop + RR + FD - j - 1)
                              && ((unsigned)y < HH);
#pragma unroll
                for (int c = 0; c < 8; ++c) nw[j-1].v[c] = act ? acc[c] : 0.f;
                if (j == FD - 1) {
#pragma unroll
                    for (int c = 0; c < 8; ++c)
                        mz = fmaxf(mz, fabsf(nw[j-1].v[c]));
                }
            } else {
                if (y >= ytop && y < ytop + RR) {
#pragma unroll
                    for (int c = 0; c < 8; ++c) mw = fmaxf(mw, fabsf(acc[c]));
                    if (op) {
                        float4* q = reinterpret_cast<float4*>(
                            op + (size_t)y * WW + (lane << 3));
                        q[0] = make_float4(acc[0], acc[1], acc[2], acc[3]);
                        q[1] = make_float4(acc[4], acc[5], acc[6], acc[7]);
                    }
                }
            }
        }
#pragma unroll
        for (int l = 0; l < FD - 1; ++l) { lt[l] = lm[l]; lm[l] = nw[l]; }
        u2 = u1; u1 = u0; u0 = un;
    }

#pragma unroll
    for (int o = 32; o; o >>= 1) {
        mz = fmaxf(mz, __shfl_xor(mz, o, 64));
        mw = fmaxf(mw, __shfl_xor(mw, o, 64));
    }
    if (lane == 0) {
        pmz[b * NS + stripe] = mz;
        pmw[b * NS + stripe] = mw;
    }
}

// m = max|v20| / max|v19|; taus[it*BB + b]
__global__ __launch_bounds__(64) void tau_k(
    const float* __restrict__ pmz, const float* __restrict__ pmw,
    float* __restrict__ taus)
{
    const int b = blockIdx.x, t = threadIdx.x;
    float vz = (t < NS) ? pmz[b * NS + t] : 0.f;
    float vw = (t < NS) ? pmw[b * NS + t] : 0.f;
#pragma unroll
    for (int o = 32; o; o >>= 1) {
        vz = fmaxf(vz, __shfl_xor(vz, o, 64));
        vw = fmaxf(vw, __shfl_xor(vw, o, 64));
    }
    if (t < N_CHEBY) {
        const float m = vw / vz;
        const double rr = cos(M_PI * (2.0 * t + 1.0) / (2.0 * N_CHEBY));
        const float denom = m + m / 3.0f - (m / 3.0f - m) * (float)rr;
        taus[t * BB + b] = 2.0f / denom;
    }
}

// ---------------------------------------------------------------------------
// Barrier-free fused Chebyshev pass: champion R15 structure, but f-ring depth
// 8 (power of 2): slot = p & 7, tap j = (p-j) & 7 — kills the per-step '%6'
// magic-multiply chains and dynamic-address formation on the tap-read path.
// Slot-reuse period 8 > max lag FD=5, so ring semantics are unchanged;
// pre-write reads still feed only act=false rows.
// ---------------------------------------------------------------------------
template<int RRv>
__global__ __launch_bounds__(256, 2) void cheby_wave2(
    const float* __restrict__ xin, const float* __restrict__ fin,
    const float* __restrict__ kern, const float* __restrict__ tauv,
    float* __restrict__ xout)
{
    constexpr int STEPSv = RRv + 2 * FD;
    __shared__ float fring[4][RSLOTS][8][64];   // 64 KB: 4 waves x 8 slots
    const int lane = threadIdx.x & 63;
    const int wid  = threadIdx.x >> 6;
    const int b = blockIdx.y;
    const int stripe = (blockIdx.x << 2) + wid;
    const int ytop = stripe * RRv;
    float (*fr)[8][64] = fring[wid];

    const float* kb = kern + b * 9;
    const float k00=kb[0],k01=kb[1],k02=kb[2],k10=kb[3],k11=kb[4],k12=kb[5],
                k20=kb[6],k21=kb[7],k22=kb[8];
    float tau[FD];
#pragma unroll
    for (int j = 0; j < FD; ++j) tau[j] = tauv[j * BB + b];

    const float* xp = xin + (size_t)b * PLANE;
    const float* fp = fin + (size_t)b * PLANE;
    float* op = xout + (size_t)b * PLANE;

    F8 u2 = {}, u1 = {};
    F8 lt[FD - 1] = {}, lm[FD - 1] = {};
    F8 u0 = ldrow(xp, ytop - FD, lane, (unsigned)(ytop - FD) < HH);

#pragma unroll 2
    for (int p = 0; p < STEPSv; ++p) {
        const int yL = ytop - FD + p;
        F8 un = ldrow(xp, yL + 1, lane,
                      (p < STEPSv - 1) && ((unsigned)(yL + 1) < HH));
        F8 fn = ldrow(fp, yL, lane, (p < STEPSv - 1) && ((unsigned)yL < HH));

        // f taps: level j uses slot (p-j) & 7; conflict-free scalar reads
        F8 ft[FD];
#pragma unroll
        for (int j = 1; j <= FD; ++j) {
            const int sp = (p - j) & (RSLOTS - 1);
#pragma unroll
            for (int c = 0; c < 8; ++c) ft[j-1].v[c] = fr[sp][c][lane];
        }

        F8 nw[FD - 1];
        {   // level 1: row y = yL-1; x1 = x0 + tau0*(f - A x0)
            float acc[8] = {0,0,0,0,0,0,0,0};
            racc8(u2, k00,k01,k02, acc);
            racc8(u1, k10,k11,k12, acc);
            racc8(u0, k20,k21,k22, acc);
            const int y = yL - 1;
            const bool act = (y >= ytop - (FD-1)) && (y <= ytop + RRv + FD - 2)
                          && ((unsigned)y < HH);
#pragma unroll
            for (int c = 0; c < 8; ++c)
                nw[0].v[c] = act ? fmaf(tau[0], ft[0].v[c] - acc[c], u1.v[c]) : 0.f;
        }
#pragma unroll
        for (int j = 2; j <= FD; ++j) {
            float acc[8] = {0,0,0,0,0,0,0,0};
            racc8(lt[j-2], k00,k01,k02, acc);
            racc8(lm[j-2], k10,k11,k12, acc);
            racc8(nw[j-2], k20,k21,k22, acc);
            const int y = yL - j;
            if (j < FD) {
                const bool act = (y >= ytop - (FD-j)) && (y <= ytop + RRv + FD - j - 1)
                              && ((unsigned)y < HH);
#pragma unroll
                for (int c = 0; c < 8; ++c)
                    nw[j-1].v[c] =
                        act ? fmaf(tau[j-1], ft[j-1].v[c] - acc[c], lm[j-2].v[c])
                            : 0.f;
            } else {
                if (y >= ytop && y < ytop + RRv) {
                    float4* q = reinterpret_cast<float4*>(
                        op + (size_t)y * WW + (lane << 3));
                    float o0 = fmaf(tau[FD-1], ft[FD-1].v[0] - acc[0], lm[j-2].v[0]);
                    float o1 = fmaf(tau[FD-1], ft[FD-1].v[1] - acc[1], lm[j-2].v[1]);
                    float o2 = fmaf(tau[FD-1], ft[FD-1].v[2] - acc[2], lm[j-2].v[2]);
                    float o3 = fmaf(tau[FD-1], ft[FD-1].v[3] - acc[3], lm[j-2].v[3]);
                    q[0] = make_float4(o0, o1, o2, o3);
                    o0 = fmaf(tau[FD-1], ft[FD-1].v[4] - acc[4], lm[j-2].v[4]);
                    o1 = fmaf(tau[FD-1], ft[FD-1].v[5] - acc[5], lm[j-2].v[5]);
                    o2 = fmaf(tau[FD-1], ft[FD-1].v[6] - acc[6], lm[j-2].v[6]);
                    o3 = fmaf(tau[FD-1], ft[FD-1].v[7] - acc[7], lm[j-2].v[7]);
                    q[1] = make_float4(o0, o1, o2, o3);
                }
            }
        }

        // write f(yL) into slot p & 7 (first read at step p+1)
        if (p < STEPSv - 1) {
            const int sp = p & (RSLOTS - 1);
#pragma unroll
            for (int c = 0; c < 8; ++c) fr[sp][c][lane] = fn.v[c];
        }

#pragma unroll
        for (int l = 0; l < FD - 1; ++l) { lt[l] = lm[l]; lm[l] = nw[l]; }
        u2 = u1; u1 = u0; u0 = un;
    }
}

extern "C" void kernel_launch(void* const* d_in, const int* in_sizes, int n_in,
                              void* d_out, int out_size, void* d_ws, size_t ws_size,
                              hipStream_t stream)
{
    const float* x_in = (const float*)d_in[0];
    const float* f_in = (const float*)d_in[1];
    const float* k_in = (const float*)d_in[2];
    const float* u_in = (const float*)d_in[3];
    float* out = (float*)d_out;

    float* bufA = (float*)d_ws;                 // 64 MB field
    float* pmW0 = bufA + (size_t)BB * PLANE;    // [BB*NS] each
    float* pmW1 = pmW0 + BB * NS;
    float* pmZ  = pmW1 + BB * NS;
    float* taus = pmZ  + BB * NS;               // [15*BB]

    dim3 blk(256);
    dim3 grdc(NS / 4, BB);                      // conv: 256 blocks, 1 stripe/wave

    // ---- 4 fused power passes (5 levels each = 20 iterations) ----
    conv_wave<<<grdc, blk, 0, stream>>>(u_in, k_in, nullptr, bufA, pmW0, pmZ);
    conv_wave<<<grdc, blk, 0, stream>>>(bufA, k_in, pmW0, out,  pmW1, pmZ);
    conv_wave<<<grdc, blk, 0, stream>>>(out,  k_in, pmW1, bufA, pmW0, pmZ);
    conv_wave<<<grdc, blk, 0, stream>>>(bufA, k_in, pmW0, nullptr, pmW1, pmZ);

    tau_k<<<BB, 64, 0, stream>>>(pmZ, pmW1, taus);

    // ---- 3 fused Chebyshev passes, RR=16 (512 blocks, 8 waves/CU) ----
    dim3 grdy((HH / 16) / 4, BB);
    cheby_wave2<16><<<grdy, blk, 0, stream>>>(x_in, f_in, k_in, taus,          out);
    cheby_wave2<16><<<grdy, blk, 0, stream>>>(out,  f_in, k_in, taus + 5 * BB, bufA);
    cheby_wave2<16><<<grdy, blk, 0, stream>>>(bufA, f_in, k_in, taus + 10 * BB, out);
}

// Round 22
// 342.937 us; speedup vs baseline: 1.0259x; 1.0259x over previous
//
#include <hip/hip_runtime.h>

#define BB 64
#define HH 512
#define WW 512
#define PLANE (HH * WW)
#define N_CHEBY 15
#define FD 5
#define RR 32
#define NS (HH / RR)          // 16 stripes (conv)
#define STEPS (RR + 2 * FD)   // 42

struct F8 { float v[8]; };

// wave-wide lane shifts with zero fill at wave edge (= plane column padding)
__device__ __forceinline__ float wshr1(float x) {  // lane i <- lane i-1; lane0 <- 0
    return __int_as_float(__builtin_amdgcn_update_dpp(
        0, __float_as_int(x), 0x138, 0xF, 0xF, true));
}
__device__ __forceinline__ float wshl1(float x) {  // lane i <- lane i+1; lane63 <- 0
    return __int_as_float(__builtin_amdgcn_update_dpp(
        0, __float_as_int(x), 0x130, 0xF, 0xF, true));
}

// lane owns cols [8*lane, 8*lane+8)
__device__ __forceinline__ F8 ldrow(const float* plane, int y, int lane, bool ok) {
    F8 r;
    if (ok) {
        const float4* p =
            reinterpret_cast<const float4*>(plane + (size_t)y * WW + (lane << 3));
        const float4 a = p[0], b = p[1];
        r.v[0] = a.x; r.v[1] = a.y; r.v[2] = a.z; r.v[3] = a.w;
        r.v[4] = b.x; r.v[5] = b.y; r.v[6] = b.z; r.v[7] = b.w;
    } else {
#pragma unroll
        for (int i = 0; i < 8; ++i) r.v[i] = 0.f;
    }
    return r;
}

__device__ __forceinline__ void racc8(const F8& r, float k0, float k1, float k2,
                                      float acc[8]) {
    const float lf = wshr1(r.v[7]);   // col 8L-1
    const float rt = wshl1(r.v[0]);   // col 8L+8
    acc[0] = fmaf(k0, lf, fmaf(k1, r.v[0], fmaf(k2, r.v[1], acc[0])));
#pragma unroll
    for (int c = 1; c < 7; ++c)
        acc[c] = fmaf(k0, r.v[c-1], fmaf(k1, r.v[c], fmaf(k2, r.v[c+1], acc[c])));
    acc[7] = fmaf(k0, r.v[6], fmaf(k1, r.v[7], fmaf(k2, rt, acc[7])));
}

// ---------------------------------------------------------------------------
// Barrier-free fused power pass (CHAMPION config: FD=5 @ RR=32, lb(256,1),
// grid 256 — ~31 us/pass). Wave owns one stripe; lag-1 level chain; DPP
// halos; pure-register (no LDS, no barriers).
// mz = stripe max|v_{FD-1}|, mw = stripe max|v_FD|. out==null -> no store.
// ---------------------------------------------------------------------------
__global__ __launch_bounds__(256, 1) void conv_wave(
    const float* __restrict__ in, const float* __restrict__ kern,
    const float* __restrict__ pm_prev, float* __restrict__ out,
    float* __restrict__ pmw, float* __restrict__ pmz)
{
    const int lane = threadIdx.x & 63;
    const int wid  = threadIdx.x >> 6;
    const int b = blockIdx.y;
    const int stripe = (blockIdx.x << 2) + wid;
    const int ytop = stripe * RR;

    float invv = 1.f;
    if (pm_prev) {
        float v = (lane < NS) ? pm_prev[b * NS + lane] : 0.f;
#pragma unroll
        for (int o = 32; o; o >>= 1) v = fmaxf(v, __shfl_xor(v, o, 64));
        invv = 1.f / v;
    }

    const float* kb = kern + b * 9;
    const float k00=kb[0],k01=kb[1],k02=kb[2],k10=kb[3],k11=kb[4],k12=kb[5],
                k20=kb[6],k21=kb[7],k22=kb[8];
    const float* ip = in + (size_t)b * PLANE;
    float* op = out ? out + (size_t)b * PLANE : nullptr;

    F8 u2 = {}, u1 = {};
    F8 lt[FD - 1] = {}, lm[FD - 1] = {};
    float mz = 0.f, mw = 0.f;
    F8 u0 = ldrow(ip, ytop - FD, lane, (unsigned)(ytop - FD) < HH);

#pragma unroll 6
    for (int p = 0; p < STEPS; ++p) {
        const int yL = ytop - FD + p;
        F8 un = ldrow(ip, yL + 1, lane,
                      (p < STEPS - 1) && ((unsigned)(yL + 1) < HH));

        F8 nw[FD - 1];
        {   // level 1: row y = yL-1
            float acc[8] = {0,0,0,0,0,0,0,0};
            racc8(u2, k00,k01,k02, acc);
            racc8(u1, k10,k11,k12, acc);
            racc8(u0, k20,k21,k22, acc);
            const int y = yL - 1;
            const bool act = (y >= ytop - (FD-1)) && (y <= ytop + RR + FD - 2)
                          && ((unsigned)y < HH);
#pragma unroll
            for (int c = 0; c < 8; ++c) nw[0].v[c] = act ? acc[c] * invv : 0.f;
        }
#pragma unroll
        for (int j = 2; j <= FD; ++j) {
            float acc[8] = {0,0,0,0,0,0,0,0};
            racc8(lt[j-2], k00,k01,k02, acc);
            racc8(lm[j-2], k10,k11,k12, acc);
            racc8(nw[j-2], k20,k21,k22, acc);
            const int y = yL - j;
            if (j < FD) {
                const bool act = (y >= ytop - (FD-j)) && (y <= ytop + RR + FD - j - 1)
                              && ((unsigned)y < HH);
#pragma unroll
                for (int c = 0; c < 8; ++c) nw[j-1].v[c] = act ? acc[c] : 0.f;
                if (j == FD - 1) {
#pragma unroll
                    for (int c = 0; c < 8; ++c)
                        mz = fmaxf(mz, fabsf(nw[j-1].v[c]));
                }
            } else {
                if (y >= ytop && y < ytop + RR) {
#pragma unroll
                    for (int c = 0; c < 8; ++c) mw = fmaxf(mw, fabsf(acc[c]));
                    if (op) {
                        float4* q = reinterpret_cast<float4*>(
                            op + (size_t)y * WW + (lane << 3));
                        q[0] = make_float4(acc[0], acc[1], acc[2], acc[3]);
                        q[1] = make_float4(acc[4], acc[5], acc[6], acc[7]);
                    }
                }
            }
        }
#pragma unroll
        for (int l = 0; l < FD - 1; ++l) { lt[l] = lm[l]; lm[l] = nw[l]; }
        u2 = u1; u1 = u0; u0 = un;
    }

#pragma unroll
    for (int o = 32; o; o >>= 1) {
        mz = fmaxf(mz, __shfl_xor(mz, o, 64));
        mw = fmaxf(mw, __shfl_xor(mw, o, 64));
    }
    if (lane == 0) {
        pmz[b * NS + stripe] = mz;
        pmw[b * NS + stripe] = mw;
    }
}

// m = max|v20| / max|v19|; taus[it*BB + b]
__global__ __launch_bounds__(64) void tau_k(
    const float* __restrict__ pmz, const float* __restrict__ pmw,
    float* __restrict__ taus)
{
    const int b = blockIdx.x, t = threadIdx.x;
    float vz = (t < NS) ? pmz[b * NS + t] : 0.f;
    float vw = (t < NS) ? pmw[b * NS + t] : 0.f;
#pragma unroll
    for (int o = 32; o; o >>= 1) {
        vz = fmaxf(vz, __shfl_xor(vz, o, 64));
        vw = fmaxf(vw, __shfl_xor(vw, o, 64));
    }
    if (t < N_CHEBY) {
        const float m = vw / vz;
        const double rr = cos(M_PI * (2.0 * t + 1.0) / (2.0 * N_CHEBY));
        const float denom = m + m / 3.0f - (m / 3.0f - m) * (float)rr;
        taus[t * BB + b] = 2.0f / denom;
    }
}

// ---------------------------------------------------------------------------
// Barrier-free fused Chebyshev pass (CHAMPION round-15 version): RRv=16
// stripes, transposed conflict-free f-ring fr[slot][c][lane] (bank = lane%32,
// 2-way aliasing = free). Level j at step p taps f(yL-j) = slot (p-j) mod 6;
// pre-write reads feed only act=false rows.
// ---------------------------------------------------------------------------
template<int RRv>
__global__ __launch_bounds__(256, 2) void cheby_wave2(
    const float* __restrict__ xin, const float* __restrict__ fin,
    const float* __restrict__ kern, const float* __restrict__ tauv,
    float* __restrict__ xout)
{
    constexpr int STEPSv = RRv + 2 * FD;
    __shared__ float fring[4][FD + 1][8][64];   // 48 KB: 4 waves x 6 slots
    const int lane = threadIdx.x & 63;
    const int wid  = threadIdx.x >> 6;
    const int b = blockIdx.y;
    const int stripe = (blockIdx.x << 2) + wid;
    const int ytop = stripe * RRv;
    float (*fr)[8][64] = fring[wid];

    const float* kb = kern + b * 9;
    const float k00=kb[0],k01=kb[1],k02=kb[2],k10=kb[3],k11=kb[4],k12=kb[5],
                k20=kb[6],k21=kb[7],k22=kb[8];
    float tau[FD];
#pragma unroll
    for (int j = 0; j < FD; ++j) tau[j] = tauv[j * BB + b];

    const float* xp = xin + (size_t)b * PLANE;
    const float* fp = fin + (size_t)b * PLANE;
    float* op = xout + (size_t)b * PLANE;

    F8 u2 = {}, u1 = {};
    F8 lt[FD - 1] = {}, lm[FD - 1] = {};
    F8 u0 = ldrow(xp, ytop - FD, lane, (unsigned)(ytop - FD) < HH);

#pragma unroll 2
    for (int p = 0; p < STEPSv; ++p) {
        const int yL = ytop - FD + p;
        F8 un = ldrow(xp, yL + 1, lane,
                      (p < STEPSv - 1) && ((unsigned)(yL + 1) < HH));
        F8 fn = ldrow(fp, yL, lane, (p < STEPSv - 1) && ((unsigned)yL < HH));

        // f taps: level j uses slot (p-j) mod 6; conflict-free scalar reads
        F8 ft[FD];
#pragma unroll
        for (int j = 1; j <= FD; ++j) {
            const int sp = (p + (FD + 1) - j) % (FD + 1);
#pragma unroll
            for (int c = 0; c < 8; ++c) ft[j-1].v[c] = fr[sp][c][lane];
        }

        F8 nw[FD - 1];
        {   // level 1: row y = yL-1; x1 = x0 + tau0*(f - A x0)
            float acc[8] = {0,0,0,0,0,0,0,0};
            racc8(u2, k00,k01,k02, acc);
            racc8(u1, k10,k11,k12, acc);
            racc8(u0, k20,k21,k22, acc);
            const int y = yL - 1;
            const bool act = (y >= ytop - (FD-1)) && (y <= ytop + RRv + FD - 2)
                          && ((unsigned)y < HH);
#pragma unroll
            for (int c = 0; c < 8; ++c)
                nw[0].v[c] = act ? fmaf(tau[0], ft[0].v[c] - acc[c], u1.v[c]) : 0.f;
        }
#pragma unroll
        for (int j = 2; j <= FD; ++j) {
            float acc[8] = {0,0,0,0,0,0,0,0};
            racc8(lt[j-2], k00,k01,k02, acc);
            racc8(lm[j-2], k10,k11,k12, acc);
            racc8(nw[j-2], k20,k21,k22, acc);
            const int y = yL - j;
            if (j < FD) {
                const bool act = (y >= ytop - (FD-j)) && (y <= ytop + RRv + FD - j - 1)
                              && ((unsigned)y < HH);
#pragma unroll
                for (int c = 0; c < 8; ++c)
                    nw[j-1].v[c] =
                        act ? fmaf(tau[j-1], ft[j-1].v[c] - acc[c], lm[j-2].v[c])
                            : 0.f;
            } else {
                if (y >= ytop && y < ytop + RRv) {
                    float4* q = reinterpret_cast<float4*>(
                        op + (size_t)y * WW + (lane << 3));
                    float o0 = fmaf(tau[FD-1], ft[FD-1].v[0] - acc[0], lm[j-2].v[0]);
                    float o1 = fmaf(tau[FD-1], ft[FD-1].v[1] - acc[1], lm[j-2].v[1]);
                    float o2 = fmaf(tau[FD-1], ft[FD-1].v[2] - acc[2], lm[j-2].v[2]);
                    float o3 = fmaf(tau[FD-1], ft[FD-1].v[3] - acc[3], lm[j-2].v[3]);
                    q[0] = make_float4(o0, o1, o2, o3);
                    o0 = fmaf(tau[FD-1], ft[FD-1].v[4] - acc[4], lm[j-2].v[4]);
                    o1 = fmaf(tau[FD-1], ft[FD-1].v[5] - acc[5], lm[j-2].v[5]);
                    o2 = fmaf(tau[FD-1], ft[FD-1].v[6] - acc[6], lm[j-2].v[6]);
                    o3 = fmaf(tau[FD-1], ft[FD-1].v[7] - acc[7], lm[j-2].v[7]);
                    q[1] = make_float4(o0, o1, o2, o3);
                }
            }
        }

        // write f(yL) into slot p mod 6 (first read at step p+1)
        if (p < STEPSv - 1) {
            const int sp = p % (FD + 1);
#pragma unroll
            for (int c = 0; c < 8; ++c) fr[sp][c][lane] = fn.v[c];
        }

#pragma unroll
        for (int l = 0; l < FD - 1; ++l) { lt[l] = lm[l]; lm[l] = nw[l]; }
        u2 = u1; u1 = u0; u0 = un;
    }
}

extern "C" void kernel_launch(void* const* d_in, const int* in_sizes, int n_in,
                              void* d_out, int out_size, void* d_ws, size_t ws_size,
                              hipStream_t stream)
{
    const float* x_in = (const float*)d_in[0];
    const float* f_in = (const float*)d_in[1];
    const float* k_in = (const float*)d_in[2];
    const float* u_in = (const float*)d_in[3];
    float* out = (float*)d_out;

    float* bufA = (float*)d_ws;                 // 64 MB field
    float* pmW0 = bufA + (size_t)BB * PLANE;    // [BB*NS] each
    float* pmW1 = pmW0 + BB * NS;
    float* pmZ  = pmW1 + BB * NS;
    float* taus = pmZ  + BB * NS;               // [15*BB]

    dim3 blk(256);
    dim3 grdc(NS / 4, BB);                      // conv: 256 blocks, 1 stripe/wave

    // ---- 4 fused power passes (5 levels each = 20 iterations) ----
    conv_wave<<<grdc, blk, 0, stream>>>(u_in, k_in, nullptr, bufA, pmW0, pmZ);
    conv_wave<<<grdc, blk, 0, stream>>>(bufA, k_in, pmW0, out,  pmW1, pmZ);
    conv_wave<<<grdc, blk, 0, stream>>>(out,  k_in, pmW1, bufA, pmW0, pmZ);
    conv_wave<<<grdc, blk, 0, stream>>>(bufA, k_in, pmW0, nullptr, pmW1, pmZ);

    tau_k<<<BB, 64, 0, stream>>>(pmZ, pmW1, taus);

    // ---- 3 fused Chebyshev passes, RR=16 (512 blocks, 8 waves/CU) ----
    dim3 grdy((HH / 16) / 4, BB);
    cheby_wave2<16><<<grdy, blk, 0, stream>>>(x_in, f_in, k_in, taus,          out);
    cheby_wave2<16><<<grdy, blk, 0, stream>>>(out,  f_in, k_in, taus + 5 * BB, bufA);
    cheby_wave2<16><<<grdy, blk, 0, stream>>>(bufA, f_in, k_in, taus + 10 * BB, out);
}